// Round 10
// baseline (26.399 us; speedup 1.0000x reference)
//
#include <hip/hip_runtime.h>
#include <math.h>

// B=2, N=512, DIM=3, C_IN=64, C_OUT=64
// ws layout (floats): s[1024] | gm4[1024*256] | pk[1024*512*4 u32]
#define WS_S   0
#define WS_GM4 1024
#define WS_PK  (1024 + 262144)

typedef unsigned int u32;
typedef const __attribute__((address_space(1))) void g_void;
typedef __attribute__((address_space(3))) void l_void;

// ---------------------------------------------------------------------------
// Prep, grid 1280 x 256:
//  bx < 1024:  zero out[bx*192 .. +192)
//  bx < 256:   4 bj each:  s[bj] = sum_c ||geom[bj,:,c]||*norm_w[c] + norm_b
//              gm4[bj][co] = {geom[bj,:,:] @ theta[:64,co], 0}  (float4)
//  bx >= 256:  bi = bx-256: pk[bi][j] = {e2, adj, bf16rtz(r0,r1), r2}
//              e2 = nw64*||rel|| + emb   (NO s -> no intra-dispatch dep;
//              s folded in main).  Pack = ~9 VALU/pair (v_perm for r0r1).
// ---------------------------------------------------------------------------
__global__ __launch_bounds__(256) void prep_kernel(
    const float* __restrict__ geom,    // [1024,3,64]
    const float* __restrict__ adj,     // [1024,512]
    const float* __restrict__ rel,     // [1024,512,3]
    const float* __restrict__ emb,     // [1024,512]
    const float* __restrict__ theta,   // [65,64]
    const float* __restrict__ norm_w,  // [65]
    const float* __restrict__ norm_b,  // [1]
    float* __restrict__ s,             // [1024]
    float* __restrict__ gm4,           // [1024,64,4]
    uint4* __restrict__ pk,            // [1024,512]
    float* __restrict__ out)           // [1024,192]
{
    const int bx  = blockIdx.x;
    const int tid = threadIdx.x;

    if (bx < 1024 && tid < 192) out[(size_t)bx * 192 + tid] = 0.f;

    if (bx < 256) {
        const int sub  = tid >> 6;      // which of 4 bj
        const int lane = tid & 63;      // = c, and = co
        const int bj   = bx * 4 + sub;
        __shared__ float g[4][192];     // [d*64 + c]
        const float* gb = geom + (size_t)bj * 192;
        g[sub][lane]       = gb[lane];
        g[sub][lane + 64]  = gb[lane + 64];
        g[sub][lane + 128] = gb[lane + 128];
        __syncthreads();

        {
            float g0 = g[sub][lane], g1 = g[sub][64 + lane], g2 = g[sub][128 + lane];
            float t = sqrtf(g0 * g0 + g1 * g1 + g2 * g2) * norm_w[lane];
            for (int off = 32; off > 0; off >>= 1) t += __shfl_down(t, off);
            if (lane == 0) s[bj] = t + norm_b[0];
        }

        float a0 = 0.f, a1 = 0.f, a2 = 0.f;
        for (int c = 0; c < 64; ++c) {
            float th = theta[c * 64 + lane];
            a0 = fmaf(g[sub][c],       th, a0);
            a1 = fmaf(g[sub][64 + c],  th, a1);
            a2 = fmaf(g[sub][128 + c], th, a2);
        }
        *reinterpret_cast<float4*>(gm4 + (size_t)bj * 256 + lane * 4) =
            make_float4(a0, a1, a2, 0.f);
    } else {
        const int bi = bx - 256;
        const float nw64 = norm_w[64];
        #pragma unroll
        for (int k = 0; k < 2; ++k) {
            int j = tid + k * 256;
            size_t p = (size_t)bi * 512 + j;
            float r0 = rel[p * 3], r1 = rel[p * 3 + 1], r2 = rel[p * 3 + 2];
            float e2 = fmaf(nw64, sqrtf(r0 * r0 + r1 * r1 + r2 * r2), emb[p]);
            uint4 q;
            q.x = __builtin_bit_cast(u32, e2);
            q.y = __builtin_bit_cast(u32, adj[p]);
            q.z = __builtin_amdgcn_perm(__builtin_bit_cast(u32, r1),
                                        __builtin_bit_cast(u32, r0),
                                        0x07060302u);   // {r1.hi16, r0.hi16}
            q.w = __builtin_bit_cast(u32, r2);
            pk[p] = q;
        }
    }
}

// ---------------------------------------------------------------------------
// Main, grid 512 = (b*256 + iq*2 + jh), 512 thr = 8 waves (16 waves/CU).
// Block = (b, i-quad, j-half). Wave = 32-j chunk x 4 i; lane = co.
// pk tile (16 KB) staged via global_load_lds dwordx4 -- 16 DMA instrs
// replace R9's ~22-VALU/pair in-kernel pack (the hidden cost R9 missed).
// Inner: 1 broadcast ds_read_b128/pair + 11 VALU/pair; gm via coalesced
// dwordx4/j reused x4. s folded per-j: bej = fmaf(al, s_j, be);
// w = adj * relu(fmaf(al, e2, bej))   (adj >= 0).
// 8-wave LDS reduce; two jh halves combine via atomicAdd into prep-zeroed
// out (2 commutative addends -> deterministic).
// ---------------------------------------------------------------------------
__global__ __launch_bounds__(512) void main_kernel(
    const uint4* __restrict__ pk,      // [1024,512]
    const float* __restrict__ s_arr,   // [1024]
    const float* __restrict__ gm4,     // [1024,64,4]
    const float* __restrict__ theta,   // [65,64]
    const float* __restrict__ alpha,   // [64]
    const float* __restrict__ beta,    // [64]
    float* __restrict__ out)           // [1024,192]
{
    const int bx   = blockIdx.x;
    const int jh   = bx & 1;
    const int iq   = (bx >> 1) & 127;
    const int b    = bx >> 8;
    const int tid  = threadIdx.x;      // 0..511
    const int lane = tid & 63;         // co
    const int wv   = tid >> 6;         // 0..7
    const int bi0  = b * 512 + iq * 4;
    const int j0   = jh * 256;

    __shared__ uint4 pk_l[4][256];     // 16 KB, i-major (linear DMA dest)
    __shared__ float s_l[256];
    __shared__ float red[8][768];      // 24 KB

    // ---- stage pk tile: 16 units of 1KB; wave wv does units wv, wv+8 ----
    const uint4* srcbase = pk + (size_t)bi0 * 512 + j0;
    #pragma unroll
    for (int u = 0; u < 2; ++u) {
        int unit = wv + u * 8;                 // 0..15
        int il = unit >> 2, jg = unit & 3;
        __builtin_amdgcn_global_load_lds(
            (g_void*)(srcbase + (size_t)il * 512 + jg * 64 + lane),
            (l_void*)((char*)&pk_l[0][0] + unit * 1024), 16, 0, 0);
    }
    if (tid < 256) s_l[tid] = s_arr[b * 512 + j0 + tid];
    __syncthreads();                   // drains vmcnt + lgkmcnt

    const float al  = alpha[lane];
    const float be  = beta[lane];
    const float t64 = theta[64 * 64 + lane];

    const float4* gmv =
        (const float4*)gm4 + ((size_t)(b * 512 + j0 + wv * 32)) * 64 + lane;

    float acc[4][3];
    #pragma unroll
    for (int il = 0; il < 4; ++il)
        acc[il][0] = acc[il][1] = acc[il][2] = 0.f;

    #pragma unroll 4
    for (int jj = 0; jj < 32; ++jj) {
        float4 g   = gmv[(size_t)jj * 64];
        float  sj  = s_l[wv * 32 + jj];        // broadcast b32, amortized /4
        float  bej = fmaf(al, sj, be);
        #pragma unroll
        for (int il = 0; il < 4; ++il) {
            uint4 q = pk_l[il][wv * 32 + jj];  // broadcast b128
            float e2 = __builtin_bit_cast(float, q.x);
            float av = __builtin_bit_cast(float, q.y);
            float r0 = __builtin_bit_cast(float, q.z << 16);
            float r1 = __builtin_bit_cast(float, q.z & 0xFFFF0000u);
            float r2 = __builtin_bit_cast(float, q.w);
            float w  = av * fmaxf(fmaf(al, e2, bej), 0.f);
            acc[il][0] = fmaf(w, fmaf(r0, t64, g.x), acc[il][0]);
            acc[il][1] = fmaf(w, fmaf(r1, t64, g.y), acc[il][1]);
            acc[il][2] = fmaf(w, fmaf(r2, t64, g.z), acc[il][2]);
        }
    }

    // ---- 8-wave reduce (lane-contiguous b32, conflict-free) ----
    float* rw = &red[wv][lane];
    #pragma unroll
    for (int il = 0; il < 4; ++il) {
        rw[il * 192]       = acc[il][0];
        rw[il * 192 + 64]  = acc[il][1];
        rw[il * 192 + 128] = acc[il][2];
    }
    __syncthreads();

    for (int k = tid; k < 768; k += 512) {
        float v = 0.f;
        #pragma unroll
        for (int w8 = 0; w8 < 8; ++w8) v += red[w8][k];
        int il = k / 192, r = k - il * 192;
        atomicAdd(&out[(size_t)(bi0 + il) * 192 + r], v);
    }
}

extern "C" void kernel_launch(void* const* d_in, const int* in_sizes, int n_in,
                              void* d_out, int out_size, void* d_ws, size_t ws_size,
                              hipStream_t stream) {
    const float* geom   = (const float*)d_in[0];
    const float* adj    = (const float*)d_in[1];
    const float* rel    = (const float*)d_in[2];
    const float* emb    = (const float*)d_in[3];
    const float* theta  = (const float*)d_in[4];
    const float* norm_w = (const float*)d_in[5];
    const float* norm_b = (const float*)d_in[6];
    const float* alpha  = (const float*)d_in[7];
    const float* beta   = (const float*)d_in[8];
    float* out = (float*)d_out;

    float* ws  = (float*)d_ws;
    float* s   = ws + WS_S;
    float* gm4 = ws + WS_GM4;
    uint4* pk  = (uint4*)(ws + WS_PK);

    prep_kernel<<<1280, 256, 0, stream>>>(geom, adj, rel, emb, theta, norm_w,
                                          norm_b, s, gm4, pk, out);
    main_kernel<<<512, 512, 0, stream>>>(pk, s, gm4, theta, alpha, beta, out);
}